// Round 2
// baseline (562.824 us; speedup 1.0000x reference)
//
#include <hip/hip_runtime.h>
#include <cstdint>
#include <cstddef>

typedef __bf16 bf16_t;
typedef __bf16 bf16x8 __attribute__((ext_vector_type(8)));
typedef __bf16 bf16x4 __attribute__((ext_vector_type(4)));
typedef float  f32x4  __attribute__((ext_vector_type(4)));

#define MFMA(a, b, c) __builtin_amdgcn_mfma_f32_16x16x32_bf16((a), (b), (c), 0, 0, 0)

// Problem constants: BS=64, S=128, DM=512, H=8, DK=DV=512, PRED=96, NF=65536

// ---------------------------------------------------------------- converts
__global__ __launch_bounds__(256) void k_convert(const float* __restrict__ in,
                                                 bf16_t* __restrict__ out, int n) {
  int i = (blockIdx.x * 256 + threadIdx.x) * 4;
  if (i < n) {
    float4 v = *(const float4*)(in + i);
    bf16x4 o;
    o[0] = (bf16_t)v.x; o[1] = (bf16_t)v.y; o[2] = (bf16_t)v.z; o[3] = (bf16_t)v.w;
    *(bf16x4*)(out + i) = o;
  }
}

// out[c][r] = (bf16) in[r][c]   (R,C multiples of 32)
__global__ __launch_bounds__(256) void k_transpose_convert(const float* __restrict__ in,
                                                           bf16_t* __restrict__ out,
                                                           int R, int C) {
  __shared__ float tile[32][33];
  int tx = threadIdx.x & 31, ty = threadIdx.x >> 5;
  int c0 = blockIdx.x * 32, r0 = blockIdx.y * 32;
#pragma unroll
  for (int j = 0; j < 4; ++j)
    tile[ty + j * 8][tx] = in[(size_t)(r0 + ty + j * 8) * C + c0 + tx];
  __syncthreads();
#pragma unroll
  for (int j = 0; j < 4; ++j)
    out[(size_t)(c0 + ty + j * 8) * R + r0 + tx] = (bf16_t)tile[tx][ty + j * 8];
}

// batched bf16 transpose: in [b][R][C] -> out [b][C][R], grid (C/32, R/32, B)
__global__ __launch_bounds__(256) void k_transpose_b16(const bf16_t* __restrict__ in,
                                                       bf16_t* __restrict__ out,
                                                       int R, int C) {
  __shared__ bf16_t tile[32][34];
  size_t base = (size_t)blockIdx.z * R * C;
  int tx = threadIdx.x & 31, ty = threadIdx.x >> 5;
  int c0 = blockIdx.x * 32, r0 = blockIdx.y * 32;
#pragma unroll
  for (int j = 0; j < 4; ++j)
    tile[ty + j * 8][tx] = in[base + (size_t)(r0 + ty + j * 8) * C + c0 + tx];
  __syncthreads();
#pragma unroll
  for (int j = 0; j < 4; ++j)
    out[base + (size_t)(c0 + ty + j * 8) * R + r0 + tx] = tile[tx][ty + j * 8];
}

// ---------------------------------------------------------------- GEMM
// C[M][N] = A[M][K] @ Bt[N][K]^T + bias, optional relu.
// OUTMODE 0: row-major [M][N].  OUTMODE 1: QKV scatter out[b][h][s][d],
//   m=b*128+s, n=h*512+d  (fixed S=128,H=8,D=512; b is stripe-local).
template <int OUTMODE, int RELU>
__global__ __launch_bounds__(256) void k_gemm(const bf16_t* __restrict__ A,
                                              const bf16_t* __restrict__ Bt,
                                              const float* __restrict__ bias,
                                              bf16_t* __restrict__ C,
                                              int M, int N, int K) {
  constexpr int BK = 64;
  __shared__ __align__(16) bf16_t As[128 * BK];
  __shared__ __align__(16) bf16_t Bs[128 * BK];
  const int tid = threadIdx.x;
  const int lane = tid & 63;
  const int wave = tid >> 6;
  const int wr = (wave >> 1) * 64, wc = (wave & 1) * 64;
  const int m0 = blockIdx.x * 128, n0 = blockIdx.y * 128;
  const int lr = lane & 15;
  const int lk = (lane >> 4) * 8;
  const int sr = tid >> 3;          // staging row (0..31)
  const int sc = (tid & 7) * 8;     // staging col
  f32x4 acc[4][4] = {};

  for (int kt = 0; kt < K; kt += BK) {
#pragma unroll
    for (int i = 0; i < 4; ++i) {
      int r = i * 32 + sr;
      *(bf16x8*)(As + r * BK + sc) = *(const bf16x8*)(A + (size_t)(m0 + r) * K + kt + sc);
      *(bf16x8*)(Bs + r * BK + sc) = *(const bf16x8*)(Bt + (size_t)(n0 + r) * K + kt + sc);
    }
    __syncthreads();
#pragma unroll
    for (int kk = 0; kk < 2; ++kk) {
      bf16x8 af[4], bfr[4];
#pragma unroll
      for (int i = 0; i < 4; ++i)
        af[i] = *(const bf16x8*)(As + (wr + i * 16 + lr) * BK + kk * 32 + lk);
#pragma unroll
      for (int j = 0; j < 4; ++j)
        bfr[j] = *(const bf16x8*)(Bs + (wc + j * 16 + lr) * BK + kk * 32 + lk);
#pragma unroll
      for (int i = 0; i < 4; ++i)
#pragma unroll
        for (int j = 0; j < 4; ++j)
          acc[i][j] = MFMA(af[i], bfr[j], acc[i][j]);
    }
    __syncthreads();
  }

  const int frow = (lane >> 4) * 4;
#pragma unroll
  for (int j = 0; j < 4; ++j) {
    int gn = n0 + wc + j * 16 + lr;
    float bv = bias ? bias[gn] : 0.0f;
#pragma unroll
    for (int i = 0; i < 4; ++i) {
#pragma unroll
      for (int q = 0; q < 4; ++q) {
        int gm = m0 + wr + i * 16 + frow + q;
        float v = acc[i][j][q] + bv;
        if (RELU) v = v > 0.0f ? v : 0.0f;
        bf16_t ov = (bf16_t)v;
        if (OUTMODE == 0) {
          C[(size_t)gm * N + gn] = ov;
        } else {
          int b = gm >> 7, s = gm & 127, h = gn >> 9, d = gn & 511;
          C[((size_t)((b * 8 + h) * 128 + s) << 9) + d] = ov;
        }
      }
    }
  }
}

// ---------------------------------------------------------------- attention
// One block per stripe-local (b,h). Q,K,V in [b][h][s][d] bf16.
// scores = QK^T*scale + prev; softmax; O = P V -> out [b][s][h*512+d] bf16.
__global__ __launch_bounds__(256) void k_attn(const bf16_t* __restrict__ Q,
                                              const bf16_t* __restrict__ Km,
                                              const bf16_t* __restrict__ V,
                                              const float* __restrict__ prev,
                                              const float* __restrict__ scale_p,
                                              bf16_t* __restrict__ O) {
  __shared__ __align__(16) bf16_t Pm[128][136];
  __shared__ __align__(16) bf16_t Stage[16384];
  bf16_t* As = Stage;          // Q tile [128][64]
  bf16_t* Bs = Stage + 8192;   // K tile [128][64]

  const int tid = threadIdx.x;
  const int lane = tid & 63;
  const int wave = tid >> 6;
  const int lr = lane & 15;
  const int lk = (lane >> 4) * 8;
  const int frow = (lane >> 4) * 4;
  const int bh = blockIdx.x;  // stripe-local b*8+h
  const size_t base = (size_t)bh * 128 * 512;
  const int sr = tid >> 3, sc = (tid & 7) * 8;
  const int wrow = wave * 32;

  // ---- phase A: scores
  f32x4 acc[2][8] = {};
  for (int kt = 0; kt < 512; kt += 64) {
#pragma unroll
    for (int i = 0; i < 4; ++i) {
      int r = i * 32 + sr;
      *(bf16x8*)(As + r * 64 + sc) = *(const bf16x8*)(Q + base + (size_t)r * 512 + kt + sc);
      *(bf16x8*)(Bs + r * 64 + sc) = *(const bf16x8*)(Km + base + (size_t)r * 512 + kt + sc);
    }
    __syncthreads();
#pragma unroll
    for (int kk = 0; kk < 2; ++kk) {
      bf16x8 af[2], bfr[8];
#pragma unroll
      for (int i = 0; i < 2; ++i)
        af[i] = *(const bf16x8*)(As + (wrow + i * 16 + lr) * 64 + kk * 32 + lk);
#pragma unroll
      for (int j = 0; j < 8; ++j)
        bfr[j] = *(const bf16x8*)(Bs + (j * 16 + lr) * 64 + kk * 32 + lk);
#pragma unroll
      for (int i = 0; i < 2; ++i)
#pragma unroll
        for (int j = 0; j < 8; ++j)
          acc[i][j] = MFMA(af[i], bfr[j], acc[i][j]);
    }
    __syncthreads();
  }

  // ---- softmax in registers (row lives in a 16-lane group)
  const float scl = scale_p[0];
#pragma unroll
  for (int i = 0; i < 2; ++i) {
#pragma unroll
    for (int q = 0; q < 4; ++q) {
      const int row = wrow + i * 16 + frow + q;
      const float* prow = prev + ((size_t)bh * 128 + row) * 128;
      float mx = -3.4e38f;
#pragma unroll
      for (int j = 0; j < 8; ++j) {
        float v = acc[i][j][q] * scl + prow[j * 16 + lr];
        acc[i][j][q] = v;
        mx = fmaxf(mx, v);
      }
      mx = fmaxf(mx, __shfl_xor(mx, 1));
      mx = fmaxf(mx, __shfl_xor(mx, 2));
      mx = fmaxf(mx, __shfl_xor(mx, 4));
      mx = fmaxf(mx, __shfl_xor(mx, 8));
      float sum = 0.0f;
#pragma unroll
      for (int j = 0; j < 8; ++j) {
        float p = __expf(acc[i][j][q] - mx);
        acc[i][j][q] = p;
        sum += p;
      }
      sum += __shfl_xor(sum, 1);
      sum += __shfl_xor(sum, 2);
      sum += __shfl_xor(sum, 4);
      sum += __shfl_xor(sum, 8);
      float inv = 1.0f / sum;
#pragma unroll
      for (int j = 0; j < 8; ++j)
        Pm[row][j * 16 + lr] = (bf16_t)(acc[i][j][q] * inv);
    }
  }
  __syncthreads();

  // ---- phase B: O = P V
  bf16_t* Vt = Stage;  // [64][136] d-major
  const int b = bh >> 3, h = bh & 7;
  for (int dt = 0; dt < 512; dt += 64) {
#pragma unroll
    for (int i = 0; i < 4; ++i) {
      int r = i * 32 + sr;  // s index
      bf16x8 v8 = *(const bf16x8*)(V + base + (size_t)r * 512 + dt + sc);
#pragma unroll
      for (int j = 0; j < 8; ++j) Vt[(sc + j) * 136 + r] = v8[j];
    }
    __syncthreads();
    f32x4 oacc[2][4] = {};
#pragma unroll
    for (int kk = 0; kk < 4; ++kk) {
      bf16x8 af[2], bfr[4];
#pragma unroll
      for (int i = 0; i < 2; ++i)
        af[i] = *(const bf16x8*)(&Pm[wrow + i * 16 + lr][kk * 32 + lk]);
#pragma unroll
      for (int j = 0; j < 4; ++j)
        bfr[j] = *(const bf16x8*)(Vt + (j * 16 + lr) * 136 + kk * 32 + lk);
#pragma unroll
      for (int i = 0; i < 2; ++i)
#pragma unroll
        for (int j = 0; j < 4; ++j)
          oacc[i][j] = MFMA(af[i], bfr[j], oacc[i][j]);
    }
#pragma unroll
    for (int i = 0; i < 2; ++i)
#pragma unroll
      for (int j = 0; j < 4; ++j)
#pragma unroll
        for (int q = 0; q < 4; ++q) {
          int srow = wrow + i * 16 + frow + q;
          int dcol = dt + j * 16 + lr;
          O[((size_t)((b * 128 + srow) * 8 + h)) * 512 + dcol] = (bf16_t)oacc[i][j][q];
        }
    __syncthreads();
  }
}

// ---------------------------------------------------------------- head (split-K)
__global__ __launch_bounds__(256) void k_head_partial(const bf16_t* __restrict__ Z,
                                                      const bf16_t* __restrict__ WhT,
                                                      float* __restrict__ part) {
  __shared__ __align__(16) bf16_t As[64 * 64];
  __shared__ __align__(16) bf16_t Bs[96 * 64];
  const int tid = threadIdx.x, lane = tid & 63, wave = tid >> 6;
  const int wr = (wave >> 1) * 32, wc = (wave & 1) * 48;
  const int lr = lane & 15, lk = (lane >> 4) * 8, frow = (lane >> 4) * 4;
  const int k0 = blockIdx.x * 512;
  const int sr = tid >> 3, sc = (tid & 7) * 8;
  f32x4 acc[2][3] = {};
  for (int kt = 0; kt < 512; kt += 64) {
#pragma unroll
    for (int i = 0; i < 2; ++i) {
      int r = i * 32 + sr;
      *(bf16x8*)(As + r * 64 + sc) = *(const bf16x8*)(Z + (size_t)r * 65536 + k0 + kt + sc);
    }
#pragma unroll
    for (int i = 0; i < 3; ++i) {
      int r = i * 32 + sr;
      *(bf16x8*)(Bs + r * 64 + sc) = *(const bf16x8*)(WhT + (size_t)r * 65536 + k0 + kt + sc);
    }
    __syncthreads();
#pragma unroll
    for (int kk = 0; kk < 2; ++kk) {
      bf16x8 af[2], bfr[3];
#pragma unroll
      for (int i = 0; i < 2; ++i)
        af[i] = *(const bf16x8*)(As + (wr + i * 16 + lr) * 64 + kk * 32 + lk);
#pragma unroll
      for (int j = 0; j < 3; ++j)
        bfr[j] = *(const bf16x8*)(Bs + (wc + j * 16 + lr) * 64 + kk * 32 + lk);
#pragma unroll
      for (int i = 0; i < 2; ++i)
#pragma unroll
        for (int j = 0; j < 3; ++j)
          acc[i][j] = MFMA(af[i], bfr[j], acc[i][j]);
    }
    __syncthreads();
  }
#pragma unroll
  for (int i = 0; i < 2; ++i)
#pragma unroll
    for (int j = 0; j < 3; ++j)
#pragma unroll
      for (int q = 0; q < 4; ++q) {
        int m = wr + i * 16 + frow + q;
        int n = wc + j * 16 + lr;
        part[(size_t)blockIdx.x * 6144 + m * 96 + n] = acc[i][j][q];
      }
}

__global__ __launch_bounds__(256) void k_head_reduce(const float* __restrict__ part,
                                                     const float* __restrict__ bias,
                                                     float* __restrict__ out) {
  int idx = blockIdx.x * 256 + threadIdx.x;
  if (idx >= 6144) return;
  float s = bias[idx % 96];
  for (int kb = 0; kb < 128; ++kb) s += part[(size_t)kb * 6144 + idx];
  out[idx] = s;
}

// diagnostic: report ws_size via absmax
__global__ void k_sentinel(float* out, int n, float val) {
  int i = blockIdx.x * 256 + threadIdx.x;
  if (i < n) out[i] = val;
}

// ---------------------------------------------------------------- launch
extern "C" void kernel_launch(void* const* d_in, const int* in_sizes, int n_in,
                              void* d_out, int out_size, void* d_ws, size_t ws_size,
                              hipStream_t stream) {
  const float* x    = (const float*)d_in[0];
  const float* prev = (const float*)d_in[1];
  const float* Wq = (const float*)d_in[2];   const float* bq = (const float*)d_in[3];
  const float* Wk = (const float*)d_in[4];   const float* bk = (const float*)d_in[5];
  const float* Wv = (const float*)d_in[6];   const float* bv = (const float*)d_in[7];
  const float* Wo = (const float*)d_in[8];   const float* bo = (const float*)d_in[9];
  const float* scale = (const float*)d_in[10];
  const float* Wi1 = (const float*)d_in[11]; const float* bi1 = (const float*)d_in[12];
  const float* Wi2 = (const float*)d_in[13]; const float* bi2 = (const float*)d_in[14];
  const float* Wt1 = (const float*)d_in[15]; const float* bt1 = (const float*)d_in[16];
  const float* Wt2 = (const float*)d_in[17]; const float* bt2 = (const float*)d_in[18];
  const float* Wh = (const float*)d_in[19];  const float* bh = (const float*)d_in[20];
  float* out = (float*)d_out;

  // Fixed footprint: 58,785,792 B (+ carve pad). Stripe: 4*SB MiB.
  const size_t FIXED = 58785792ull + 8192;  // pad slack
  int SB = 0;
  for (int cand : {32, 16, 8, 4, 2, 1}) {
    if (FIXED + 4ull * (size_t)cand * 1048576ull <= ws_size) { SB = cand; break; }
  }
  if (SB == 0) {  // report ws_size via absmax (value in bytes)
    k_sentinel<<<24, 256, 0, stream>>>(out, 6144, (float)ws_size);
    return;
  }
  const int NST = 64 / SB;

  char* p = (char*)d_ws;
  auto carve = [&](size_t bytes) {
    char* r = p;
    p += (bytes + 255) & ~(size_t)255;
    return r;
  };
  bf16_t* xb   = (bf16_t*)carve((size_t)8192 * 512 * 2);
  bf16_t* wqT  = (bf16_t*)carve((size_t)4096 * 512 * 2);
  bf16_t* wkT  = (bf16_t*)carve((size_t)4096 * 512 * 2);
  bf16_t* wvT  = (bf16_t*)carve((size_t)4096 * 512 * 2);
  bf16_t* woT  = (bf16_t*)carve((size_t)512 * 4096 * 2);
  bf16_t* wi1T = (bf16_t*)carve((size_t)128 * 128 * 2);
  bf16_t* wi2T = (bf16_t*)carve((size_t)128 * 128 * 2);
  bf16_t* wt1T = (bf16_t*)carve((size_t)512 * 512 * 2);
  bf16_t* wt2T = (bf16_t*)carve((size_t)512 * 512 * 2);
  bf16_t* whT  = (bf16_t*)carve((size_t)96 * 65536 * 2);
  bf16_t* o1b  = (bf16_t*)carve((size_t)8192 * 512 * 2);
  bf16_t* bufB = (bf16_t*)carve((size_t)8192 * 512 * 2);
  float*  hp   = (float*)carve((size_t)128 * 64 * 96 * 4);
  bf16_t* qs   = (bf16_t*)carve((size_t)SB * 1048576);
  bf16_t* ks   = (bf16_t*)carve((size_t)SB * 1048576);
  bf16_t* vs   = (bf16_t*)carve((size_t)SB * 1048576);
  bf16_t* obs  = (bf16_t*)carve((size_t)SB * 1048576);

  dim3 blk(256);
  // ---- converts
  k_convert<<<4096, blk, 0, stream>>>(x, xb, 8192 * 512);
  k_transpose_convert<<<dim3(128, 16), blk, 0, stream>>>(Wq, wqT, 512, 4096);
  k_transpose_convert<<<dim3(128, 16), blk, 0, stream>>>(Wk, wkT, 512, 4096);
  k_transpose_convert<<<dim3(128, 16), blk, 0, stream>>>(Wv, wvT, 512, 4096);
  k_transpose_convert<<<dim3(16, 128), blk, 0, stream>>>(Wo, woT, 4096, 512);
  k_transpose_convert<<<dim3(4, 4), blk, 0, stream>>>(Wi1, wi1T, 128, 128);
  k_transpose_convert<<<dim3(4, 4), blk, 0, stream>>>(Wi2, wi2T, 128, 128);
  k_transpose_convert<<<dim3(16, 16), blk, 0, stream>>>(Wt1, wt1T, 512, 512);
  k_transpose_convert<<<dim3(16, 16), blk, 0, stream>>>(Wt2, wt2T, 512, 512);
  k_transpose_convert<<<dim3(3, 2048), blk, 0, stream>>>(Wh, whT, 65536, 96);

  // ---- striped attention path
  for (int st = 0; st < NST; ++st) {
    const bf16_t* xs = xb + (size_t)st * SB * 128 * 512;
    k_gemm<1, 0><<<dim3(SB, 32), blk, 0, stream>>>(xs, wqT, bq, qs, SB * 128, 4096, 512);
    k_gemm<1, 0><<<dim3(SB, 32), blk, 0, stream>>>(xs, wkT, bk, ks, SB * 128, 4096, 512);
    k_gemm<1, 0><<<dim3(SB, 32), blk, 0, stream>>>(xs, wvT, bv, vs, SB * 128, 4096, 512);
    k_attn<<<SB * 8, blk, 0, stream>>>(qs, ks, vs,
                                       prev + (size_t)st * SB * 8 * 128 * 128, scale, obs);
    k_gemm<0, 0><<<dim3(SB, 4), blk, 0, stream>>>(obs, woT, bo,
                                                  o1b + (size_t)st * SB * 128 * 512,
                                                  SB * 128, 512, 4096);
  }

  // ---- InterPatchMixing (over S): transpose, 2 gemms, transpose back
  k_transpose_b16<<<dim3(16, 4, 64), blk, 0, stream>>>(o1b, bufB, 128, 512);  // -> [b][512][128]
  k_gemm<0, 1><<<dim3(256, 1), blk, 0, stream>>>(bufB, wi1T, bi1, o1b, 32768, 128, 128);
  k_gemm<0, 0><<<dim3(256, 1), blk, 0, stream>>>(o1b, wi2T, bi2, bufB, 32768, 128, 128);
  k_transpose_b16<<<dim3(4, 16, 64), blk, 0, stream>>>(bufB, o1b, 512, 128);  // -> [b][128][512]

  // ---- IntraPatchMixing
  k_gemm<0, 1><<<dim3(64, 4), blk, 0, stream>>>(o1b, wt1T, bt1, bufB, 8192, 512, 512);
  k_gemm<0, 0><<<dim3(64, 4), blk, 0, stream>>>(bufB, wt2T, bt2, o1b, 8192, 512, 512);

  // ---- Flatten head: split-K=128 partials + deterministic reduce
  k_head_partial<<<128, blk, 0, stream>>>(o1b, whT, hp);
  k_head_reduce<<<24, blk, 0, stream>>>(hp, bh, out);
}